// Round 1
// baseline (591.498 us; speedup 1.0000x reference)
//
#include <hip/hip_runtime.h>

// DepthwiseRREUp: out[b,c,g, 2i+di, 2j+dj] = x[b,c,g,i,j] * rot90(dw[c], g)[di][dj]
// Pure broadcast upsample, memory-bound (134 MB read + 537 MB write).
//
// Layout constants (from reference): B=8, C=256, G=4, H=W=64, K=2.
//   x   : [B, C, G, 64, 64]  fp32
//   dw  : [C, 1, 2, 2]       fp32  (4 floats per channel, contiguous)
//   out : [B, C, G, 128, 128] fp32
//
// One thread handles 2 adjacent input pixels -> writes one float4 to each of
// two output rows (perfectly coalesced 16B/lane stores).

__global__ __launch_bounds__(256) void DepthwiseRREUp_kernel(
    const float* __restrict__ x,
    const float* __restrict__ dw,
    float* __restrict__ out) {
    const int t = blockIdx.x * blockDim.x + threadIdx.x;  // one per float2 of x

    // t = ((m*64 + i)*32 + j2), m = b*1024 + c*4 + g
    const int j2   = t & 31;        // input col pair index (j = 2*j2)
    const int rest = t >> 5;
    const int i    = rest & 63;     // input row
    const int m    = rest >> 6;     // fused [b, c, g]
    const int cg   = m & 1023;      // c*4 + g
    const int c    = cg >> 2;
    const int g    = cg & 3;        // block-uniform (m constant within a block)

    // Coalesced 8B input load.
    const float2 xv = *reinterpret_cast<const float2*>(x + ((size_t)t << 1));
    // Wave-uniform 16B filter load: {a,b,c,d} = dw[c] row-major.
    const float4 w = *reinterpret_cast<const float4*>(dw + (c << 2));

    // rot90 CCW by g of [[a,b],[c,d]]:
    //   g=0: [[a,b],[c,d]]  g=1: [[b,d],[a,c]]  g=2: [[d,c],[b,a]]  g=3: [[c,a],[d,b]]
    float f00, f01, f10, f11;
    switch (g) {
        case 0:  f00 = w.x; f01 = w.y; f10 = w.z; f11 = w.w; break;
        case 1:  f00 = w.y; f01 = w.w; f10 = w.x; f11 = w.z; break;
        case 2:  f00 = w.w; f01 = w.z; f10 = w.y; f11 = w.x; break;
        default: f00 = w.z; f01 = w.x; f10 = w.w; f11 = w.y; break;
    }

    // Output: [m, 128, 128]; rows 2i and 2i+1, cols 4*j2 .. 4*j2+3.
    const size_t obase = (size_t)m * (128 * 128) + (size_t)(2 * i) * 128 + (j2 << 2);

    const float4 o0 = make_float4(xv.x * f00, xv.x * f01, xv.y * f00, xv.y * f01);
    const float4 o1 = make_float4(xv.x * f10, xv.x * f11, xv.y * f10, xv.y * f11);

    *reinterpret_cast<float4*>(out + obase)       = o0;
    *reinterpret_cast<float4*>(out + obase + 128) = o1;
}

extern "C" void kernel_launch(void* const* d_in, const int* in_sizes, int n_in,
                              void* d_out, int out_size, void* d_ws, size_t ws_size,
                              hipStream_t stream) {
    const float* x  = (const float*)d_in[0];   // [8,256,4,64,64]
    const float* dw = (const float*)d_in[1];   // [256,1,2,2]
    float* out      = (float*)d_out;           // [8,256,4,128,128]

    const int n_threads = in_sizes[0] / 2;     // 33,554,432 / 2 = 16,777,216
    const int block = 256;
    const int grid = n_threads / block;        // 65,536 (exact)

    DepthwiseRREUp_kernel<<<grid, block, 0, stream>>>(x, dw, out);
}